// Round 11
// baseline (1119.232 us; speedup 1.0000x reference)
//
#include <hip/hip_runtime.h>
#include <hip/hip_bf16.h>

#define CC 64

typedef __attribute__((ext_vector_type(8))) short s16x8;
typedef __attribute__((ext_vector_type(4))) float f32x4;

__device__ __forceinline__ unsigned short f2b(float f) {   // f32 -> bf16 bits, RNE
    unsigned u = __float_as_uint(f);
    u += 0x7FFF + ((u >> 16) & 1);
    return (unsigned short)(u >> 16);
}
__device__ __forceinline__ unsigned fmono(float f) {       // order-preserving f32->u32
    unsigned u = __float_as_uint(f);
    return u ^ ((unsigned)((int)u >> 31) | 0x80000000u);
}

// ---- node kernel + fused dst-histogram ---------------------------------------------------
__global__ __launch_bounds__(256, 2) void node_proj_kernel(
    const float* __restrict__ x,
    const float* __restrict__ W_in, const float* __restrict__ b_in,
    const float* __restrict__ W_src, const float* __restrict__ W_dst,
    const float* __restrict__ W_lin, const float* __restrict__ aW1,
    float* __restrict__ AS, float* __restrict__ AD, float* __restrict__ xvv,
    const int* __restrict__ ei, unsigned* __restrict__ cnt, int N, int E)
{
    __shared__ float xt[64][68];
    __shared__ float ht[64][68];
    const int t = threadIdx.x, lane = t & 63, quad = t >> 6;
    const int n0 = blockIdx.x * 64;
    float wreg[64];

    #pragma unroll 4
    for (int i = 0; i < 16; ++i) {
        int r = i*4 + quad, n = n0 + r;
        xt[r][lane] = (n < N) ? x[(size_t)n*CC + lane] : 0.f;
    }
    #pragma unroll
    for (int k4 = 0; k4 < 16; ++k4)
        *(float4*)&wreg[k4*4] = *(const float4*)&W_in[(size_t)lane*CC + k4*4];
    const float bi = b_in[lane];
    __syncthreads();

    #pragma unroll 2
    for (int i = 0; i < 16; ++i) {
        int r = i*4 + quad;
        float acc = bi;
        #pragma unroll
        for (int k4 = 0; k4 < 16; ++k4) {
            float4 xx = *(const float4*)&xt[r][k4*4];
            acc += xx.x*wreg[k4*4+0] + xx.y*wreg[k4*4+1]
                 + xx.z*wreg[k4*4+2] + xx.w*wreg[k4*4+3];
        }
        ht[r][lane] = fmaxf(acc, 0.f);
    }
    __syncthreads();

    const float* Wm[2] = {W_src, W_dst};
    float* Om[2] = {AS, AD};
    #pragma unroll
    for (int m = 0; m < 2; ++m) {
        #pragma unroll
        for (int k4 = 0; k4 < 16; ++k4)
            *(float4*)&wreg[k4*4] = *(const float4*)&Wm[m][(size_t)lane*CC + k4*4];
        #pragma unroll 2
        for (int i = 0; i < 16; ++i) {
            int r = i*4 + quad;
            float acc = 0.f;
            #pragma unroll
            for (int k4 = 0; k4 < 16; ++k4) {
                float4 xx = *(const float4*)&ht[r][k4*4];
                acc += xx.x*wreg[k4*4+0] + xx.y*wreg[k4*4+1]
                     + xx.z*wreg[k4*4+2] + xx.w*wreg[k4*4+3];
            }
            xt[r][lane] = acc;
        }
        __syncthreads();
        #pragma unroll
        for (int k = 0; k < 64; ++k) wreg[k] = aW1[(size_t)k*CC + lane];
        #pragma unroll 2
        for (int i = 0; i < 16; ++i) {
            int r = i*4 + quad, n = n0 + r;
            float acc = 0.f;
            #pragma unroll
            for (int k4 = 0; k4 < 16; ++k4) {
                float4 xx = *(const float4*)&xt[r][k4*4];
                acc += xx.x*wreg[k4*4+0] + xx.y*wreg[k4*4+1]
                     + xx.z*wreg[k4*4+2] + xx.w*wreg[k4*4+3];
            }
            if (n < N) Om[m][(size_t)n*CC + lane] = acc;
        }
        __syncthreads();
    }

    #pragma unroll
    for (int k4 = 0; k4 < 16; ++k4)
        *(float4*)&wreg[k4*4] = *(const float4*)&W_lin[(size_t)lane*CC + k4*4];
    #pragma unroll 2
    for (int i = 0; i < 16; ++i) {
        int r = i*4 + quad, n = n0 + r;
        float acc = 0.f;
        #pragma unroll
        for (int k4 = 0; k4 < 16; ++k4) {
            float4 xx = *(const float4*)&ht[r][k4*4];
            acc += xx.x*wreg[k4*4+0] + xx.y*wreg[k4*4+1]
                 + xx.z*wreg[k4*4+2] + xx.w*wreg[k4*4+3];
        }
        if (n < N) xvv[(size_t)n*CC + lane] = acc;
    }

    // fused dst histogram (was a standalone kernel)
    const int total = E + N;
    for (int e = blockIdx.x*256 + t; e < total; e += gridDim.x*256) {
        int d = (e < E) ? min(max(ei[(size_t)E + e], 0), N-1) : (e - E);
        atomicAdd(&cnt[d], 1u);
    }
}

// ---- exclusive scan (3 kernels) + scatter ------------------------------------------------
#define SCAN_T 256
__global__ __launch_bounds__(SCAN_T) void scan1_kernel(
    const unsigned* __restrict__ cnt, unsigned* __restrict__ chunk_off,
    unsigned* __restrict__ partials, int n)
{
    __shared__ unsigned sh[SCAN_T];
    const int t = threadIdx.x, b0 = blockIdx.x * (SCAN_T*4);
    unsigned v[4], s = 0;
    #pragma unroll
    for (int i = 0; i < 4; ++i) {
        int idx = b0 + t*4 + i;
        v[i] = (idx < n) ? cnt[idx] : 0u;
        s += v[i];
    }
    sh[t] = s; __syncthreads();
    for (int d = 1; d < SCAN_T; d <<= 1) {
        unsigned xv = (t >= d) ? sh[t-d] : 0u;
        __syncthreads();
        sh[t] += xv;
        __syncthreads();
    }
    unsigned run = (t > 0) ? sh[t-1] : 0u;
    #pragma unroll
    for (int i = 0; i < 4; ++i) {
        int idx = b0 + t*4 + i;
        if (idx < n) chunk_off[idx] = run;
        run += v[i];
    }
    if (t == SCAN_T-1) partials[blockIdx.x] = sh[SCAN_T-1];
}

__global__ __launch_bounds__(1024) void scan2_kernel(unsigned* __restrict__ partials, int nb)
{
    __shared__ unsigned sh[1024];
    const int t = threadIdx.x;
    sh[t] = (t < nb) ? partials[t] : 0u; __syncthreads();
    for (int d = 1; d < 1024; d <<= 1) {
        unsigned xv = (t >= d) ? sh[t-d] : 0u;
        __syncthreads();
        sh[t] += xv;
        __syncthreads();
    }
    if (t < nb) partials[t] = (t > 0) ? sh[t-1] : 0u;
}

__global__ __launch_bounds__(256) void scan3_kernel(
    const unsigned* __restrict__ chunk_off, const unsigned* __restrict__ partials,
    unsigned* __restrict__ cursor, int n)
{
    int i = blockIdx.x*256 + threadIdx.x;
    if (i < n) cursor[i] = chunk_off[i] + partials[i >> 10];
}

__global__ __launch_bounds__(256) void scatter_kernel(
    const int* __restrict__ ei, unsigned* __restrict__ cursor,
    int2* __restrict__ rec, int N, int E)
{
    const int total = E + N;
    for (int e = blockIdx.x*256 + threadIdx.x; e < total; e += gridDim.x*256) {
        int s, d;
        if (e < E) {
            s = min(max(ei[e], 0), N-1);
            d = min(max(ei[(size_t)E + e], 0), N-1);
        } else { s = d = e - E; }
        unsigned p = atomicAdd(&cursor[d], 1u);
        rec[p] = make_int2(s, d);
    }
}

// ---- edge kernel: sorted tiles, hoisted gathers, rec prefetch, 4 waves/SIMD --------------
__global__ __launch_bounds__(256, 4) void edge_mfma_kernel(
    const int2* __restrict__ rec, const float* __restrict__ pos,
    const float* __restrict__ AD, const float* __restrict__ AS, const float* __restrict__ xv,
    const float* __restrict__ pW1, const float* __restrict__ pb1,
    const float* __restrict__ pW2, const float* __restrict__ pb2,
    const float* __restrict__ aW1, const float* __restrict__ ab1,
    const float* __restrict__ aW2, const float* __restrict__ ab2,
    float* __restrict__ esum, unsigned* __restrict__ outb,
    int N, int E)
{
    const int tid = threadIdx.x;
    const int lane = tid & 63;
    const int wid  = tid >> 6;
    const int lm = lane & 15;
    const int lg = lane >> 4;

    __shared__ __align__(16) unsigned short swt[3][64 * 72];
    __shared__ __align__(16) unsigned short tb[4][16 * 72];
    __shared__ unsigned spw[2][64];

    {
        const float* Wsrc[3] = {pW2, aW1, aW2};
        #pragma unroll
        for (int w = 0; w < 3; ++w)
            for (int idx = tid; idx < 4096; idx += 256) {
                int k = idx >> 6, o = idx & 63;
                swt[w][o*72 + k] = f2b(Wsrc[w][idx]);
            }
        if (tid < 64) {
            spw[0][tid] = (unsigned)f2b(pW1[tid])     | ((unsigned)f2b(pW1[64+tid]) << 16);
            spw[1][tid] = (unsigned)f2b(pW1[128+tid]) | ((unsigned)f2b(pb1[tid])    << 16);
        }
    }
    __syncthreads();

    float pb2v[4], ab1v[4], ab2v[4];
    #pragma unroll
    for (int tt = 0; tt < 4; ++tt) {
        pb2v[tt] = pb2[lm + 16*tt];
        ab1v[tt] = ab1[lm + 16*tt];
        ab2v[tt] = ab2[lm + 16*tt];
    }

    unsigned short* tbw = tb[wid];
    const int total = E + N;
    const int ntiles = (total + 15) >> 4;
    const int nwaves = gridDim.x * 4;
    const int tpw = (ntiles + nwaves - 1) / nwaves;
    const int gw = blockIdx.x * 4 + wid;
    const int t0 = gw * tpw;
    const int t1 = min(t0 + tpw, ntiles);
    if (t0 >= t1) return;

    // prologue: prefetch rec for first tile
    int2 rp_n, rg_n0, rg_n1, rg_n2, rg_n3;
    {
        const int base = t0 << 4;
        int ep = base + lm; if (ep >= total) ep = total - 1;
        rp_n = rec[ep];
        int e0 = base + lg*4;
        rg_n0 = rec[min(e0+0, total-1)];
        rg_n1 = rec[min(e0+1, total-1)];
        rg_n2 = rec[min(e0+2, total-1)];
        rg_n3 = rec[min(e0+3, total-1)];
    }

    for (int tile = t0; tile < t1; ++tile) {
        const int base = tile << 4;
        const int2 rp = rp_n;
        int sg[4], dg[4];
        sg[0] = rg_n0.x; dg[0] = rg_n0.y;
        sg[1] = rg_n1.x; dg[1] = rg_n1.y;
        sg[2] = rg_n2.x; dg[2] = rg_n2.y;
        sg[3] = rg_n3.x; dg[3] = rg_n3.y;
        int actm = 0;
        #pragma unroll
        for (int r = 0; r < 4; ++r)
            if (base + lg*4 + r < total) actm |= (1 << r);

        // pos diff (current)
        float q0 = pos[(size_t)rp.y*3+0] - pos[(size_t)rp.x*3+0];
        float q1 = pos[(size_t)rp.y*3+1] - pos[(size_t)rp.x*3+1];
        float q2 = pos[(size_t)rp.y*3+2] - pos[(size_t)rp.x*3+2];

        // ---- HOISTED gathers: issue before any MFMA/LDS stage ----
        float gd[4][4], gxv[4][4];
        #pragma unroll
        for (int r = 0; r < 4; ++r)
            #pragma unroll
            for (int tt = 0; tt < 4; ++tt) {
                gd[r][tt]  = AD[(size_t)dg[r]*CC + lm + 16*tt]
                           - AS[(size_t)sg[r]*CC + lm + 16*tt];
                gxv[r][tt] = xv[(size_t)sg[r]*CC + lm + 16*tt];
            }

        // ---- prefetch next tile's rec ----
        if (tile + 1 < t1) {
            const int nb = (tile + 1) << 4;
            int ep = nb + lm; if (ep >= total) ep = total - 1;
            rp_n = rec[ep];
            int e0 = nb + lg*4;
            rg_n0 = rec[min(e0+0, total-1)];
            rg_n1 = rec[min(e0+1, total-1)];
            rg_n2 = rec[min(e0+2, total-1)];
            rg_n3 = rec[min(e0+3, total-1)];
        }

        // ---- p1 = relu(pdiff@pW1 + pb1) in A-frag layout ----
        s16x8 Alo, Ahi;
        #pragma unroll
        for (int j = 0; j < 16; ++j) {
            int k = lg*8 + (j & 7) + 32*(j >> 3);
            unsigned wa = ((volatile unsigned*)spw[0])[k];
            unsigned wb = ((volatile unsigned*)spw[1])[k];
            float w0 = __uint_as_float(wa << 16);
            float w1 = __uint_as_float(wa & 0xFFFF0000u);
            float w2 = __uint_as_float(wb << 16);
            float bb = __uint_as_float(wb & 0xFFFF0000u);
            float v = fmaxf(fmaf(q0, w0, fmaf(q1, w1, fmaf(q2, w2, bb))), 0.f);
            short b = (short)f2b(v);
            if (j < 8) Alo[j] = b; else Ahi[j-8] = b;
        }

        // ---- layer 1: delta = relu(p1 @ pW2 + pb2) ----
        f32x4 dlt[4];
        #pragma unroll
        for (int tt = 0; tt < 4; ++tt) {
            s16x8 b0 = *(const s16x8*)&swt[0][(lm + 16*tt)*72 + lg*8];
            s16x8 b1 = *(const s16x8*)&swt[0][(lm + 16*tt)*72 + 32 + lg*8];
            f32x4 z = {0.f, 0.f, 0.f, 0.f};
            z = __builtin_amdgcn_mfma_f32_16x16x32_bf16(Alo, b0, z, 0, 0, 0);
            z = __builtin_amdgcn_mfma_f32_16x16x32_bf16(Ahi, b1, z, 0, 0, 0);
            #pragma unroll
            for (int r = 0; r < 4; ++r) dlt[tt][r] = fmaxf(z[r] + pb2v[tt], 0.f);
        }

        // ---- transpose 1 ----
        #pragma unroll
        for (int tt = 0; tt < 4; ++tt)
            #pragma unroll
            for (int r = 0; r < 4; ++r)
                tbw[(lg*4+r)*72 + lm + 16*tt] = f2b(dlt[tt][r]);
        __builtin_amdgcn_wave_barrier();
        s16x8 Dlo = *(const s16x8*)&tbw[lm*72 + lg*8];
        s16x8 Dhi = *(const s16x8*)&tbw[lm*72 + 32 + lg*8];
        __builtin_amdgcn_wave_barrier();

        // ---- layer 2: h1 = relu(gd + delta@aW1 + ab1) -> transpose 2 ----
        #pragma unroll
        for (int tt = 0; tt < 4; ++tt) {
            s16x8 b0 = *(const s16x8*)&swt[1][(lm + 16*tt)*72 + lg*8];
            s16x8 b1 = *(const s16x8*)&swt[1][(lm + 16*tt)*72 + 32 + lg*8];
            f32x4 z = {0.f, 0.f, 0.f, 0.f};
            z = __builtin_amdgcn_mfma_f32_16x16x32_bf16(Dlo, b0, z, 0, 0, 0);
            z = __builtin_amdgcn_mfma_f32_16x16x32_bf16(Dhi, b1, z, 0, 0, 0);
            #pragma unroll
            for (int r = 0; r < 4; ++r) {
                float v = fmaxf(z[r] + gd[r][tt] + ab1v[tt], 0.f);
                tbw[(lg*4+r)*72 + lm + 16*tt] = f2b(v);
            }
        }
        __builtin_amdgcn_wave_barrier();
        s16x8 Hlo = *(const s16x8*)&tbw[lm*72 + lg*8];
        s16x8 Hhi = *(const s16x8*)&tbw[lm*72 + 32 + lg*8];
        __builtin_amdgcn_wave_barrier();

        // ---- layer 3 + run-merged atomics (dst sorted => dg non-decreasing in r) ----
        #pragma unroll
        for (int tt = 0; tt < 4; ++tt) {
            s16x8 b0 = *(const s16x8*)&swt[2][(lm + 16*tt)*72 + lg*8];
            s16x8 b1 = *(const s16x8*)&swt[2][(lm + 16*tt)*72 + 32 + lg*8];
            f32x4 z = {0.f, 0.f, 0.f, 0.f};
            z = __builtin_amdgcn_mfma_f32_16x16x32_bf16(Hlo, b0, z, 0, 0, 0);
            z = __builtin_amdgcn_mfma_f32_16x16x32_bf16(Hhi, b1, z, 0, 0, 0);
            const int c = lm + 16*tt;
            int cur = -1; float s = 0.f, mx = 0.f;
            #pragma unroll
            for (int r = 0; r < 4; ++r) {
                if (!(actm & (1 << r))) continue;
                float a  = fmaxf(z[r] + ab2v[tt], 0.f);
                float ee = __expf(a);
                float m  = ee * (gxv[r][tt] + dlt[tt][r]);
                if (dg[r] != cur) {
                    if (cur >= 0) {
                        size_t off = (size_t)cur*CC + c;
                        atomicAdd(&esum[off], s);
                        atomicMax(&outb[off], fmono(mx));
                    }
                    cur = dg[r]; s = 0.f; mx = -INFINITY;
                }
                s += ee; mx = fmaxf(mx, m);
            }
            if (cur >= 0) {
                size_t off = (size_t)cur*CC + c;
                atomicAdd(&esum[off], s);
                atomicMax(&outb[off], fmono(mx));
            }
        }
    }
}

// ---- output kernel (unchanged) -----------------------------------------------------------
__global__ __launch_bounds__(256, 2) void out_kernel(
    const unsigned* outb_in,            // aliases out -- no restrict
    const float* __restrict__ esum,
    const float* __restrict__ W_out, const float* __restrict__ b_out,
    float* out, int N)
{
    __shared__ float vt[64][68];
    const int t = threadIdx.x, lane = t & 63, quad = t >> 6;
    const int n0 = blockIdx.x * 64;
    float wreg[64];
    #pragma unroll
    for (int k4 = 0; k4 < 16; ++k4)
        *(float4*)&wreg[k4*4] = *(const float4*)&W_out[(size_t)lane*CC + k4*4];
    #pragma unroll 4
    for (int i = 0; i < 16; ++i) {
        int r = i*4 + quad, n = n0 + r;
        float v = 0.f;
        if (n < N) {
            unsigned u = outb_in[(size_t)n*CC + lane];
            u = (u >> 31) ? (u ^ 0x80000000u) : ~u;   // inverse of fmono
            v = __uint_as_float(u) / esum[(size_t)n*CC + lane];
        }
        vt[r][lane] = v;
    }
    __syncthreads();
    const float bo = b_out[lane];
    #pragma unroll 2
    for (int i = 0; i < 16; ++i) {
        int r = i*4 + quad, n = n0 + r;
        if (n >= N) continue;
        float acc = bo;
        #pragma unroll
        for (int k4 = 0; k4 < 16; ++k4) {
            float4 xx = *(const float4*)&vt[r][k4*4];
            acc += xx.x*wreg[k4*4+0] + xx.y*wreg[k4*4+1]
                 + xx.z*wreg[k4*4+2] + xx.w*wreg[k4*4+3];
        }
        out[(size_t)n*CC + lane] = fmaxf(acc, 0.f);
    }
}

extern "C" void kernel_launch(void* const* d_in, const int* in_sizes, int n_in,
                              void* d_out, int out_size, void* d_ws, size_t ws_size,
                              hipStream_t stream)
{
    const float* x     = (const float*)d_in[0];
    const float* pos   = (const float*)d_in[1];
    const int*   ei    = (const int*)d_in[2];
    const float* W_in  = (const float*)d_in[3];
    const float* b_in  = (const float*)d_in[4];
    const float* W_out = (const float*)d_in[5];
    const float* b_out = (const float*)d_in[6];
    const float* W_lin = (const float*)d_in[7];
    const float* W_src = (const float*)d_in[8];
    const float* W_dst = (const float*)d_in[9];
    const float* pW1   = (const float*)d_in[10];
    const float* pb1   = (const float*)d_in[11];
    const float* pW2   = (const float*)d_in[12];
    const float* pb2   = (const float*)d_in[13];
    const float* aW1   = (const float*)d_in[14];
    const float* ab1   = (const float*)d_in[15];
    const float* aW2   = (const float*)d_in[16];
    const float* ab2   = (const float*)d_in[17];

    const int N = in_sizes[0] / CC;
    const int E = in_sizes[2] / 2;
    const size_t nc = (size_t)N * CC;

    float* ws   = (float*)d_ws;
    float* AS   = ws;
    float* AD   = ws + nc;
    float* xvv  = ws + 2*nc;
    float* esum = ws + 3*nc;
    unsigned* cnt       = (unsigned*)(ws + 4*nc);
    unsigned* chunk_off = cnt + N;
    unsigned* cursor    = chunk_off + N;
    unsigned* partials  = cursor + N;          // 1024 entries
    size_t rec_off = ((4*nc + 3*(size_t)N + 1024) * 4 + 15) & ~(size_t)15;
    int2* rec = (int2*)((char*)d_ws + rec_off);
    unsigned* outb = (unsigned*)d_out;

    hipMemsetAsync(esum, 0, nc*sizeof(float), stream);
    hipMemsetAsync(outb, 0, nc*sizeof(float), stream);
    hipMemsetAsync(cnt, 0, (size_t)N*sizeof(unsigned), stream);

    const int nblk = (N + 63) / 64;
    node_proj_kernel<<<nblk, 256, 0, stream>>>(x, W_in, b_in, W_src, W_dst, W_lin, aW1,
                                               AS, AD, xvv, ei, cnt, N, E);
    const int nchunks = (N + 1023) / 1024;
    scan1_kernel<<<nchunks, SCAN_T, 0, stream>>>(cnt, chunk_off, partials, N);
    scan2_kernel<<<1, 1024, 0, stream>>>(partials, nchunks);
    scan3_kernel<<<(N + 255)/256, 256, 0, stream>>>(chunk_off, partials, cursor, N);
    scatter_kernel<<<2048, 256, 0, stream>>>(ei, cursor, rec, N, E);
    edge_mfma_kernel<<<2048, 256, 0, stream>>>(rec, pos, AD, AS, xvv,
                                               pW1, pb1, pW2, pb2, aW1, ab1, aW2, ab2,
                                               esum, outb, N, E);
    out_kernel<<<nblk, 256, 0, stream>>>(outb, esum, W_out, b_out, (float*)d_out, N);
}

// Round 12
// 1058.504 us; speedup vs baseline: 1.0574x; 1.0574x over previous
//
#include <hip/hip_runtime.h>
#include <hip/hip_bf16.h>

#define CC 64

typedef __attribute__((ext_vector_type(8))) short s16x8;
typedef __attribute__((ext_vector_type(4))) float f32x4;

__device__ __forceinline__ unsigned short f2b(float f) {   // f32 -> bf16 bits, RNE
    unsigned u = __float_as_uint(f);
    u += 0x7FFF + ((u >> 16) & 1);
    return (unsigned short)(u >> 16);
}
__device__ __forceinline__ unsigned fmono(float f) {       // order-preserving f32->u32
    unsigned u = __float_as_uint(f);
    return u ^ ((unsigned)((int)u >> 31) | 0x80000000u);
}

// ---- node kernel + fused dst-histogram ---------------------------------------------------
// AS/AD/xv are written in PERMUTED channel layout: channel c -> column (c&15)*4 + (c>>4),
// so the edge kernel can gather a lane's 4 channels {lm, lm+16, lm+32, lm+48} as one float4.
__global__ __launch_bounds__(256, 2) void node_proj_kernel(
    const float* __restrict__ x,
    const float* __restrict__ W_in, const float* __restrict__ b_in,
    const float* __restrict__ W_src, const float* __restrict__ W_dst,
    const float* __restrict__ W_lin, const float* __restrict__ aW1,
    float* __restrict__ AS, float* __restrict__ AD, float* __restrict__ xvv,
    const int* __restrict__ ei, unsigned* __restrict__ cnt, int N, int E)
{
    __shared__ float xt[64][68];
    __shared__ float ht[64][68];
    const int t = threadIdx.x, lane = t & 63, quad = t >> 6;
    const int n0 = blockIdx.x * 64;
    const int perm = (lane & 15) * 4 + (lane >> 4);
    float wreg[64];

    #pragma unroll 4
    for (int i = 0; i < 16; ++i) {
        int r = i*4 + quad, n = n0 + r;
        xt[r][lane] = (n < N) ? x[(size_t)n*CC + lane] : 0.f;
    }
    #pragma unroll
    for (int k4 = 0; k4 < 16; ++k4)
        *(float4*)&wreg[k4*4] = *(const float4*)&W_in[(size_t)lane*CC + k4*4];
    const float bi = b_in[lane];
    __syncthreads();

    #pragma unroll 2
    for (int i = 0; i < 16; ++i) {
        int r = i*4 + quad;
        float acc = bi;
        #pragma unroll
        for (int k4 = 0; k4 < 16; ++k4) {
            float4 xx = *(const float4*)&xt[r][k4*4];
            acc += xx.x*wreg[k4*4+0] + xx.y*wreg[k4*4+1]
                 + xx.z*wreg[k4*4+2] + xx.w*wreg[k4*4+3];
        }
        ht[r][lane] = fmaxf(acc, 0.f);
    }
    __syncthreads();

    const float* Wm[2] = {W_src, W_dst};
    float* Om[2] = {AS, AD};
    #pragma unroll
    for (int m = 0; m < 2; ++m) {
        #pragma unroll
        for (int k4 = 0; k4 < 16; ++k4)
            *(float4*)&wreg[k4*4] = *(const float4*)&Wm[m][(size_t)lane*CC + k4*4];
        #pragma unroll 2
        for (int i = 0; i < 16; ++i) {
            int r = i*4 + quad;
            float acc = 0.f;
            #pragma unroll
            for (int k4 = 0; k4 < 16; ++k4) {
                float4 xx = *(const float4*)&ht[r][k4*4];
                acc += xx.x*wreg[k4*4+0] + xx.y*wreg[k4*4+1]
                     + xx.z*wreg[k4*4+2] + xx.w*wreg[k4*4+3];
            }
            xt[r][lane] = acc;
        }
        __syncthreads();
        #pragma unroll
        for (int k = 0; k < 64; ++k) wreg[k] = aW1[(size_t)k*CC + lane];
        #pragma unroll 2
        for (int i = 0; i < 16; ++i) {
            int r = i*4 + quad, n = n0 + r;
            float acc = 0.f;
            #pragma unroll
            for (int k4 = 0; k4 < 16; ++k4) {
                float4 xx = *(const float4*)&xt[r][k4*4];
                acc += xx.x*wreg[k4*4+0] + xx.y*wreg[k4*4+1]
                     + xx.z*wreg[k4*4+2] + xx.w*wreg[k4*4+3];
            }
            if (n < N) Om[m][(size_t)n*CC + perm] = acc;
        }
        __syncthreads();
    }

    #pragma unroll
    for (int k4 = 0; k4 < 16; ++k4)
        *(float4*)&wreg[k4*4] = *(const float4*)&W_lin[(size_t)lane*CC + k4*4];
    #pragma unroll 2
    for (int i = 0; i < 16; ++i) {
        int r = i*4 + quad, n = n0 + r;
        float acc = 0.f;
        #pragma unroll
        for (int k4 = 0; k4 < 16; ++k4) {
            float4 xx = *(const float4*)&ht[r][k4*4];
            acc += xx.x*wreg[k4*4+0] + xx.y*wreg[k4*4+1]
                 + xx.z*wreg[k4*4+2] + xx.w*wreg[k4*4+3];
        }
        if (n < N) xvv[(size_t)n*CC + perm] = acc;
    }

    // fused dst histogram
    const int total = E + N;
    for (int e = blockIdx.x*256 + t; e < total; e += gridDim.x*256) {
        int d = (e < E) ? min(max(ei[(size_t)E + e], 0), N-1) : (e - E);
        atomicAdd(&cnt[d], 1u);
    }
}

// ---- exclusive scan (3 kernels) + scatter ------------------------------------------------
#define SCAN_T 256
__global__ __launch_bounds__(SCAN_T) void scan1_kernel(
    const unsigned* __restrict__ cnt, unsigned* __restrict__ chunk_off,
    unsigned* __restrict__ partials, int n)
{
    __shared__ unsigned sh[SCAN_T];
    const int t = threadIdx.x, b0 = blockIdx.x * (SCAN_T*4);
    unsigned v[4], s = 0;
    #pragma unroll
    for (int i = 0; i < 4; ++i) {
        int idx = b0 + t*4 + i;
        v[i] = (idx < n) ? cnt[idx] : 0u;
        s += v[i];
    }
    sh[t] = s; __syncthreads();
    for (int d = 1; d < SCAN_T; d <<= 1) {
        unsigned xv = (t >= d) ? sh[t-d] : 0u;
        __syncthreads();
        sh[t] += xv;
        __syncthreads();
    }
    unsigned run = (t > 0) ? sh[t-1] : 0u;
    #pragma unroll
    for (int i = 0; i < 4; ++i) {
        int idx = b0 + t*4 + i;
        if (idx < n) chunk_off[idx] = run;
        run += v[i];
    }
    if (t == SCAN_T-1) partials[blockIdx.x] = sh[SCAN_T-1];
}

__global__ __launch_bounds__(1024) void scan2_kernel(unsigned* __restrict__ partials, int nb)
{
    __shared__ unsigned sh[1024];
    const int t = threadIdx.x;
    sh[t] = (t < nb) ? partials[t] : 0u; __syncthreads();
    for (int d = 1; d < 1024; d <<= 1) {
        unsigned xv = (t >= d) ? sh[t-d] : 0u;
        __syncthreads();
        sh[t] += xv;
        __syncthreads();
    }
    if (t < nb) partials[t] = (t > 0) ? sh[t-1] : 0u;
}

__global__ __launch_bounds__(256) void scan3_kernel(
    const unsigned* __restrict__ chunk_off, const unsigned* __restrict__ partials,
    unsigned* __restrict__ cursor, int n)
{
    int i = blockIdx.x*256 + threadIdx.x;
    if (i < n) cursor[i] = chunk_off[i] + partials[i >> 10];
}

__global__ __launch_bounds__(256) void scatter_kernel(
    const int* __restrict__ ei, unsigned* __restrict__ cursor,
    int2* __restrict__ rec, int N, int E)
{
    const int total = E + N;
    for (int e = blockIdx.x*256 + threadIdx.x; e < total; e += gridDim.x*256) {
        int s, d;
        if (e < E) {
            s = min(max(ei[e], 0), N-1);
            d = min(max(ei[(size_t)E + e], 0), N-1);
        } else { s = d = e - E; }
        unsigned p = atomicAdd(&cursor[d], 1u);
        rec[p] = make_int2(s, d);
    }
}

// ---- edge kernel: sorted tiles, float4 gathers, hoist + rec prefetch, 3 waves/SIMD -------
__global__ __launch_bounds__(256, 3) void edge_mfma_kernel(
    const int2* __restrict__ rec, const float* __restrict__ pos,
    const float* __restrict__ AD, const float* __restrict__ AS, const float* __restrict__ xv,
    const float* __restrict__ pW1, const float* __restrict__ pb1,
    const float* __restrict__ pW2, const float* __restrict__ pb2,
    const float* __restrict__ aW1, const float* __restrict__ ab1,
    const float* __restrict__ aW2, const float* __restrict__ ab2,
    float* __restrict__ esum, unsigned* __restrict__ outb,
    int N, int E)
{
    const int tid = threadIdx.x;
    const int lane = tid & 63;
    const int wid  = tid >> 6;
    const int lm = lane & 15;
    const int lg = lane >> 4;

    __shared__ __align__(16) unsigned short swt[3][64 * 72];
    __shared__ __align__(16) unsigned short tb[4][16 * 72];
    __shared__ unsigned spw[2][64];

    {
        const float* Wsrc[3] = {pW2, aW1, aW2};
        #pragma unroll
        for (int w = 0; w < 3; ++w)
            for (int idx = tid; idx < 4096; idx += 256) {
                int k = idx >> 6, o = idx & 63;
                swt[w][o*72 + k] = f2b(Wsrc[w][idx]);
            }
        if (tid < 64) {
            spw[0][tid] = (unsigned)f2b(pW1[tid])     | ((unsigned)f2b(pW1[64+tid]) << 16);
            spw[1][tid] = (unsigned)f2b(pW1[128+tid]) | ((unsigned)f2b(pb1[tid])    << 16);
        }
    }
    __syncthreads();

    float pb2v[4], ab1v[4], ab2v[4];
    #pragma unroll
    for (int tt = 0; tt < 4; ++tt) {
        pb2v[tt] = pb2[lm + 16*tt];
        ab1v[tt] = ab1[lm + 16*tt];
        ab2v[tt] = ab2[lm + 16*tt];
    }

    unsigned short* tbw = tb[wid];
    const int total = E + N;
    const int ntiles = (total + 15) >> 4;
    const int nwaves = gridDim.x * 4;
    const int tpw = (ntiles + nwaves - 1) / nwaves;
    const int gw = blockIdx.x * 4 + wid;
    const int t0 = gw * tpw;
    const int t1 = min(t0 + tpw, ntiles);
    if (t0 >= t1) return;

    // prologue: prefetch rec for first tile
    int2 rp_n, rg_n0, rg_n1, rg_n2, rg_n3;
    {
        const int base = t0 << 4;
        int ep = base + lm; if (ep >= total) ep = total - 1;
        rp_n = rec[ep];
        int e0 = base + lg*4;
        rg_n0 = rec[min(e0+0, total-1)];
        rg_n1 = rec[min(e0+1, total-1)];
        rg_n2 = rec[min(e0+2, total-1)];
        rg_n3 = rec[min(e0+3, total-1)];
    }

    for (int tile = t0; tile < t1; ++tile) {
        const int base = tile << 4;
        const int2 rp = rp_n;
        int sg[4], dg[4];
        sg[0] = rg_n0.x; dg[0] = rg_n0.y;
        sg[1] = rg_n1.x; dg[1] = rg_n1.y;
        sg[2] = rg_n2.x; dg[2] = rg_n2.y;
        sg[3] = rg_n3.x; dg[3] = rg_n3.y;
        int actm = 0;
        #pragma unroll
        for (int r = 0; r < 4; ++r)
            if (base + lg*4 + r < total) actm |= (1 << r);

        // pos diff (current)
        float q0 = pos[(size_t)rp.y*3+0] - pos[(size_t)rp.x*3+0];
        float q1 = pos[(size_t)rp.y*3+1] - pos[(size_t)rp.x*3+1];
        float q2 = pos[(size_t)rp.y*3+2] - pos[(size_t)rp.x*3+2];

        // ---- HOISTED float4 gathers (permuted layout: one load = 4 channels) ----
        float gd[4][4]; float4 xv4[4];
        #pragma unroll
        for (int r = 0; r < 4; ++r) {
            const float4 a4 = *(const float4*)&AD[(size_t)dg[r]*CC + lm*4];
            const float4 s4 = *(const float4*)&AS[(size_t)sg[r]*CC + lm*4];
            xv4[r] = *(const float4*)&xv[(size_t)sg[r]*CC + lm*4];
            gd[r][0] = a4.x - s4.x; gd[r][1] = a4.y - s4.y;
            gd[r][2] = a4.z - s4.z; gd[r][3] = a4.w - s4.w;
        }

        // ---- prefetch next tile's rec ----
        if (tile + 1 < t1) {
            const int nb = (tile + 1) << 4;
            int ep = nb + lm; if (ep >= total) ep = total - 1;
            rp_n = rec[ep];
            int e0 = nb + lg*4;
            rg_n0 = rec[min(e0+0, total-1)];
            rg_n1 = rec[min(e0+1, total-1)];
            rg_n2 = rec[min(e0+2, total-1)];
            rg_n3 = rec[min(e0+3, total-1)];
        }

        // ---- p1 = relu(pdiff@pW1 + pb1) in A-frag layout ----
        s16x8 Alo, Ahi;
        #pragma unroll
        for (int j = 0; j < 16; ++j) {
            int k = lg*8 + (j & 7) + 32*(j >> 3);
            unsigned wa = ((volatile unsigned*)spw[0])[k];
            unsigned wb = ((volatile unsigned*)spw[1])[k];
            float w0 = __uint_as_float(wa << 16);
            float w1 = __uint_as_float(wa & 0xFFFF0000u);
            float w2 = __uint_as_float(wb << 16);
            float bb = __uint_as_float(wb & 0xFFFF0000u);
            float v = fmaxf(fmaf(q0, w0, fmaf(q1, w1, fmaf(q2, w2, bb))), 0.f);
            short b = (short)f2b(v);
            if (j < 8) Alo[j] = b; else Ahi[j-8] = b;
        }

        // ---- layer 1: delta = relu(p1 @ pW2 + pb2) ----
        f32x4 dlt[4];
        #pragma unroll
        for (int tt = 0; tt < 4; ++tt) {
            s16x8 b0 = *(const s16x8*)&swt[0][(lm + 16*tt)*72 + lg*8];
            s16x8 b1 = *(const s16x8*)&swt[0][(lm + 16*tt)*72 + 32 + lg*8];
            f32x4 z = {0.f, 0.f, 0.f, 0.f};
            z = __builtin_amdgcn_mfma_f32_16x16x32_bf16(Alo, b0, z, 0, 0, 0);
            z = __builtin_amdgcn_mfma_f32_16x16x32_bf16(Ahi, b1, z, 0, 0, 0);
            #pragma unroll
            for (int r = 0; r < 4; ++r) dlt[tt][r] = fmaxf(z[r] + pb2v[tt], 0.f);
        }

        // ---- transpose 1 ----
        #pragma unroll
        for (int tt = 0; tt < 4; ++tt)
            #pragma unroll
            for (int r = 0; r < 4; ++r)
                tbw[(lg*4+r)*72 + lm + 16*tt] = f2b(dlt[tt][r]);
        __builtin_amdgcn_wave_barrier();
        s16x8 Dlo = *(const s16x8*)&tbw[lm*72 + lg*8];
        s16x8 Dhi = *(const s16x8*)&tbw[lm*72 + 32 + lg*8];
        __builtin_amdgcn_wave_barrier();

        // ---- layer 2: h1 = relu(gd + delta@aW1 + ab1) -> transpose 2 ----
        // NOTE: gd[r] holds channels {lm,16+lm,32+lm,48+lm} = tt-blocks for column lm.
        #pragma unroll
        for (int tt = 0; tt < 4; ++tt) {
            s16x8 b0 = *(const s16x8*)&swt[1][(lm + 16*tt)*72 + lg*8];
            s16x8 b1 = *(const s16x8*)&swt[1][(lm + 16*tt)*72 + 32 + lg*8];
            f32x4 z = {0.f, 0.f, 0.f, 0.f};
            z = __builtin_amdgcn_mfma_f32_16x16x32_bf16(Dlo, b0, z, 0, 0, 0);
            z = __builtin_amdgcn_mfma_f32_16x16x32_bf16(Dhi, b1, z, 0, 0, 0);
            #pragma unroll
            for (int r = 0; r < 4; ++r) {
                float v = fmaxf(z[r] + gd[r][tt] + ab1v[tt], 0.f);
                tbw[(lg*4+r)*72 + lm + 16*tt] = f2b(v);
            }
        }
        __builtin_amdgcn_wave_barrier();
        s16x8 Hlo = *(const s16x8*)&tbw[lm*72 + lg*8];
        s16x8 Hhi = *(const s16x8*)&tbw[lm*72 + 32 + lg*8];
        __builtin_amdgcn_wave_barrier();

        // ---- layer 3 + run-merged atomics (dst sorted => dg non-decreasing in r) ----
        #pragma unroll
        for (int tt = 0; tt < 4; ++tt) {
            s16x8 b0 = *(const s16x8*)&swt[2][(lm + 16*tt)*72 + lg*8];
            s16x8 b1 = *(const s16x8*)&swt[2][(lm + 16*tt)*72 + 32 + lg*8];
            f32x4 z = {0.f, 0.f, 0.f, 0.f};
            z = __builtin_amdgcn_mfma_f32_16x16x32_bf16(Hlo, b0, z, 0, 0, 0);
            z = __builtin_amdgcn_mfma_f32_16x16x32_bf16(Hhi, b1, z, 0, 0, 0);
            const int c = lm + 16*tt;
            int cur = -1; float s = 0.f, mx = 0.f;
            #pragma unroll
            for (int r = 0; r < 4; ++r) {
                if (!(actm & (1 << r))) continue;
                float a  = fmaxf(z[r] + ab2v[tt], 0.f);
                float ee = __expf(a);
                float m  = ee * (((const float*)&xv4[r])[tt] + dlt[tt][r]);
                if (dg[r] != cur) {
                    if (cur >= 0) {
                        size_t off = (size_t)cur*CC + c;
                        atomicAdd(&esum[off], s);
                        atomicMax(&outb[off], fmono(mx));
                    }
                    cur = dg[r]; s = 0.f; mx = -INFINITY;
                }
                s += ee; mx = fmaxf(mx, m);
            }
            if (cur >= 0) {
                size_t off = (size_t)cur*CC + c;
                atomicAdd(&esum[off], s);
                atomicMax(&outb[off], fmono(mx));
            }
        }
    }
}

// ---- output kernel (unchanged) -----------------------------------------------------------
__global__ __launch_bounds__(256, 2) void out_kernel(
    const unsigned* outb_in,            // aliases out -- no restrict
    const float* __restrict__ esum,
    const float* __restrict__ W_out, const float* __restrict__ b_out,
    float* out, int N)
{
    __shared__ float vt[64][68];
    const int t = threadIdx.x, lane = t & 63, quad = t >> 6;
    const int n0 = blockIdx.x * 64;
    float wreg[64];
    #pragma unroll
    for (int k4 = 0; k4 < 16; ++k4)
        *(float4*)&wreg[k4*4] = *(const float4*)&W_out[(size_t)lane*CC + k4*4];
    #pragma unroll 4
    for (int i = 0; i < 16; ++i) {
        int r = i*4 + quad, n = n0 + r;
        float v = 0.f;
        if (n < N) {
            unsigned u = outb_in[(size_t)n*CC + lane];
            u = (u >> 31) ? (u ^ 0x80000000u) : ~u;   // inverse of fmono
            v = __uint_as_float(u) / esum[(size_t)n*CC + lane];
        }
        vt[r][lane] = v;
    }
    __syncthreads();
    const float bo = b_out[lane];
    #pragma unroll 2
    for (int i = 0; i < 16; ++i) {
        int r = i*4 + quad, n = n0 + r;
        if (n >= N) continue;
        float acc = bo;
        #pragma unroll
        for (int k4 = 0; k4 < 16; ++k4) {
            float4 xx = *(const float4*)&vt[r][k4*4];
            acc += xx.x*wreg[k4*4+0] + xx.y*wreg[k4*4+1]
                 + xx.z*wreg[k4*4+2] + xx.w*wreg[k4*4+3];
        }
        out[(size_t)n*CC + lane] = fmaxf(acc, 0.f);
    }
}

extern "C" void kernel_launch(void* const* d_in, const int* in_sizes, int n_in,
                              void* d_out, int out_size, void* d_ws, size_t ws_size,
                              hipStream_t stream)
{
    const float* x     = (const float*)d_in[0];
    const float* pos   = (const float*)d_in[1];
    const int*   ei    = (const int*)d_in[2];
    const float* W_in  = (const float*)d_in[3];
    const float* b_in  = (const float*)d_in[4];
    const float* W_out = (const float*)d_in[5];
    const float* b_out = (const float*)d_in[6];
    const float* W_lin = (const float*)d_in[7];
    const float* W_src = (const float*)d_in[8];
    const float* W_dst = (const float*)d_in[9];
    const float* pW1   = (const float*)d_in[10];
    const float* pb1   = (const float*)d_in[11];
    const float* pW2   = (const float*)d_in[12];
    const float* pb2   = (const float*)d_in[13];
    const float* aW1   = (const float*)d_in[14];
    const float* ab1   = (const float*)d_in[15];
    const float* aW2   = (const float*)d_in[16];
    const float* ab2   = (const float*)d_in[17];

    const int N = in_sizes[0] / CC;
    const int E = in_sizes[2] / 2;
    const size_t nc = (size_t)N * CC;

    float* ws   = (float*)d_ws;
    float* AS   = ws;
    float* AD   = ws + nc;
    float* xvv  = ws + 2*nc;
    float* esum = ws + 3*nc;
    unsigned* cnt       = (unsigned*)(ws + 4*nc);
    unsigned* chunk_off = cnt + N;
    unsigned* cursor    = chunk_off + N;
    unsigned* partials  = cursor + N;          // 1024 entries
    size_t rec_off = ((4*nc + 3*(size_t)N + 1024) * 4 + 15) & ~(size_t)15;
    int2* rec = (int2*)((char*)d_ws + rec_off);
    unsigned* outb = (unsigned*)d_out;

    hipMemsetAsync(esum, 0, nc*sizeof(float), stream);
    hipMemsetAsync(outb, 0, nc*sizeof(float), stream);
    hipMemsetAsync(cnt, 0, (size_t)N*sizeof(unsigned), stream);

    const int nblk = (N + 63) / 64;
    node_proj_kernel<<<nblk, 256, 0, stream>>>(x, W_in, b_in, W_src, W_dst, W_lin, aW1,
                                               AS, AD, xvv, ei, cnt, N, E);
    const int nchunks = (N + 1023) / 1024;
    scan1_kernel<<<nchunks, SCAN_T, 0, stream>>>(cnt, chunk_off, partials, N);
    scan2_kernel<<<1, 1024, 0, stream>>>(partials, nchunks);
    scan3_kernel<<<(N + 255)/256, 256, 0, stream>>>(chunk_off, partials, cursor, N);
    scatter_kernel<<<2048, 256, 0, stream>>>(ei, cursor, rec, N, E);
    edge_mfma_kernel<<<2048, 256, 0, stream>>>(rec, pos, AD, AS, xvv,
                                               pW1, pb1, pW2, pb2, aW1, ab1, aW2, ab2,
                                               esum, outb, N, E);
    out_kernel<<<nblk, 256, 0, stream>>>(outb, esum, W_out, b_out, (float*)d_out, N);
}